// Round 1
// baseline (4086.175 us; speedup 1.0000x reference)
//
#include <hip/hip_runtime.h>
#include <hip/hip_bf16.h>

#define HID 64
#define EDIM 32
#define NSTEPS 4

// ---------------------------------------------------------------------------
// K1: msg_base[e] = relu(edge_attr[e] @ W1^T + b1) @ W2^T + b2
// One thread per edge. edge_attr row in VGPRs, hidden[64] in VGPRs,
// weights are wave-uniform -> scalar loads through K$.
// ---------------------------------------------------------------------------
__global__ __launch_bounds__(256) void k_msg_base(
    const float* __restrict__ edge_attr,
    const float* __restrict__ W1, const float* __restrict__ b1,
    const float* __restrict__ W2, const float* __restrict__ b2,
    float* __restrict__ msg_base, int E)
{
    int e = blockIdx.x * 256 + threadIdx.x;
    if (e >= E) return;

    float ea[EDIM];
    const float4* eap = reinterpret_cast<const float4*>(edge_attr + (size_t)e * EDIM);
    #pragma unroll
    for (int q = 0; q < EDIM / 4; ++q) {
        float4 v = eap[q];
        ea[q * 4 + 0] = v.x; ea[q * 4 + 1] = v.y;
        ea[q * 4 + 2] = v.z; ea[q * 4 + 3] = v.w;
    }

    float hid[HID];
    #pragma unroll
    for (int k = 0; k < HID; ++k) {
        float acc = b1[k];
        #pragma unroll
        for (int c = 0; c < EDIM; ++c) acc += ea[c] * W1[k * EDIM + c];
        hid[k] = acc > 0.f ? acc : 0.f;
    }

    float* outp = msg_base + (size_t)e * HID;
    for (int oc = 0; oc < HID; oc += 4) {          // dynamic loop, inner unrolled
        float a0 = b2[oc + 0], a1 = b2[oc + 1], a2 = b2[oc + 2], a3 = b2[oc + 3];
        #pragma unroll
        for (int c = 0; c < HID; ++c) {
            float hv = hid[c];
            a0 += hv * W2[(oc + 0) * HID + c];
            a1 += hv * W2[(oc + 1) * HID + c];
            a2 += hv * W2[(oc + 2) * HID + c];
            a3 += hv * W2[(oc + 3) * HID + c];
        }
        float4 o; o.x = a0; o.y = a1; o.z = a2; o.w = a3;
        *reinterpret_cast<float4*>(outp + oc) = o;
    }
}

// ---------------------------------------------------------------------------
// K2: agg[i[e]] += msg_base[e] * h[j[e]]   (one thread per (edge, channel))
// msg_base read coalesced; h gather is full 256B rows (LLC-resident);
// scatter via fp32 atomics into the 25.6MB agg (L2/LLC-resident).
// ---------------------------------------------------------------------------
__global__ __launch_bounds__(256) void k_scatter(
    const float* __restrict__ msg_base, const float* __restrict__ h,
    const int* __restrict__ ei, float* __restrict__ agg, int E)
{
    size_t gid = (size_t)blockIdx.x * 256 + threadIdx.x;
    int e = (int)(gid >> 6);
    int c = (int)(gid & 63);
    if (e >= E) return;
    int dst = ei[e];        // edge_index[0][e]
    int src = ei[E + e];    // edge_index[1][e]
    float m = msg_base[(size_t)e * HID + c] * h[(size_t)src * HID + c];
    atomicAdd(agg + (size_t)dst * HID + c, m);
}

// ---------------------------------------------------------------------------
// K3: h = GRUCell(agg, h), in place. One thread per node; agg+h rows in VGPRs,
// weights wave-uniform scalar loads. 24576 FMAs/thread.
// ---------------------------------------------------------------------------
__device__ __forceinline__ float fast_sigmoid(float x) {
    return __builtin_amdgcn_rcpf(1.f + __expf(-x));
}
__device__ __forceinline__ float fast_tanh(float x) {
    // tanh(x) = 1 - 2/(exp(2x)+1)
    return 1.f - 2.f * __builtin_amdgcn_rcpf(__expf(2.f * x) + 1.f);
}

__global__ __launch_bounds__(256) void k_gru(
    const float* __restrict__ agg, float* __restrict__ h,
    const float* __restrict__ W_ih, const float* __restrict__ b_ih,
    const float* __restrict__ W_hh, const float* __restrict__ b_hh, int N)
{
    int n = blockIdx.x * 256 + threadIdx.x;
    if (n >= N) return;

    float a[HID], hh[HID];
    const float4* ap = reinterpret_cast<const float4*>(agg + (size_t)n * HID);
    const float4* hp = reinterpret_cast<const float4*>(h + (size_t)n * HID);
    #pragma unroll
    for (int q = 0; q < HID / 4; ++q) {
        float4 v = ap[q];
        a[q * 4 + 0] = v.x; a[q * 4 + 1] = v.y; a[q * 4 + 2] = v.z; a[q * 4 + 3] = v.w;
        float4 w = hp[q];
        hh[q * 4 + 0] = w.x; hh[q * 4 + 1] = w.y; hh[q * 4 + 2] = w.z; hh[q * 4 + 3] = w.w;
    }

    float4* outp = reinterpret_cast<float4*>(h + (size_t)n * HID);
    float hn4[4];
    for (int k = 0; k < HID; ++k) {               // dynamic loop, inner unrolled
        float ir = b_ih[k], iz = b_ih[HID + k], inn = b_ih[2 * HID + k];
        float hr = b_hh[k], hz = b_hh[HID + k], hnn = b_hh[2 * HID + k];
        #pragma unroll
        for (int c = 0; c < HID; ++c) {
            float av = a[c], hv = hh[c];
            ir  += av * W_ih[(0 * HID + k) * HID + c];
            iz  += av * W_ih[(1 * HID + k) * HID + c];
            inn += av * W_ih[(2 * HID + k) * HID + c];
            hr  += hv * W_hh[(0 * HID + k) * HID + c];
            hz  += hv * W_hh[(1 * HID + k) * HID + c];
            hnn += hv * W_hh[(2 * HID + k) * HID + c];
        }
        float r = fast_sigmoid(ir + hr);
        float z = fast_sigmoid(iz + hz);
        float nn = fast_tanh(inn + r * hnn);
        float hnew = (1.f - z) * nn + z * hh[k];
        hn4[k & 3] = hnew;
        if ((k & 3) == 3) {
            float4 o; o.x = hn4[0]; o.y = hn4[1]; o.z = hn4[2]; o.w = hn4[3];
            outp[k >> 2] = o;
        }
    }
}

extern "C" void kernel_launch(void* const* d_in, const int* in_sizes, int n_in,
                              void* d_out, int out_size, void* d_ws, size_t ws_size,
                              hipStream_t stream) {
    const float* h_in      = (const float*)d_in[0];
    const float* edge_attr = (const float*)d_in[1];
    const int*   ei        = (const int*)d_in[2];
    const float* W1        = (const float*)d_in[3];
    const float* b1        = (const float*)d_in[4];
    const float* W2        = (const float*)d_in[5];
    const float* b2        = (const float*)d_in[6];
    const float* W_ih      = (const float*)d_in[7];
    const float* b_ih      = (const float*)d_in[8];
    const float* W_hh      = (const float*)d_in[9];
    const float* b_hh      = (const float*)d_in[10];

    const int N = in_sizes[0] / HID;
    const int E = in_sizes[1] / EDIM;

    float* h        = (float*)d_out;                       // h lives in d_out, updated in place
    float* msg_base = (float*)d_ws;                        // E*64 floats = 256 MB
    float* agg      = (float*)d_ws + (size_t)E * HID;      // N*64 floats = 25.6 MB

    // h <- h_in
    hipMemcpyAsync(h, h_in, (size_t)N * HID * sizeof(float),
                   hipMemcpyDeviceToDevice, stream);

    // msg_base (step-invariant)
    k_msg_base<<<(E + 255) / 256, 256, 0, stream>>>(edge_attr, W1, b1, W2, b2, msg_base, E);

    for (int s = 0; s < NSTEPS; ++s) {
        hipMemsetAsync(agg, 0, (size_t)N * HID * sizeof(float), stream);
        size_t total = (size_t)E * HID;
        k_scatter<<<(unsigned)((total + 255) / 256), 256, 0, stream>>>(msg_base, h, ei, agg, E);
        k_gru<<<(N + 255) / 256, 256, 0, stream>>>(agg, h, W_ih, b_ih, W_hh, b_hh, N);
    }
}

// Round 2
// 2278.842 us; speedup vs baseline: 1.7931x; 1.7931x over previous
//
#include <hip/hip_runtime.h>
#include <hip/hip_bf16.h>

#define HID 64
#define EDIM 32
#define NSTEPS 4

__device__ __forceinline__ float bf2f(unsigned short u) {
    union { unsigned u32; float f; } x; x.u32 = ((unsigned)u) << 16; return x.f;
}
__device__ __forceinline__ unsigned short f2bf(float f) {
    union { float f; unsigned u; } x; x.f = f;
    unsigned r = x.u + 0x7fff + ((x.u >> 16) & 1);   // RNE
    return (unsigned short)(r >> 16);
}
__device__ __forceinline__ float fast_sigmoid(float x) {
    return __builtin_amdgcn_rcpf(1.f + __expf(-x));
}
__device__ __forceinline__ float fast_tanh(float x) {
    return 1.f - 2.f * __builtin_amdgcn_rcpf(__expf(2.f * x) + 1.f);
}

// ---------------------------------------------------------------------------
// K1: msg[e] = bf16( relu(edge_attr[e] @ W1^T + b1) @ W2^T + b2 )
// Thread per edge, fp32 compute, bf16 result staged in LDS, then the block
// writes 32 KB contiguous & coalesced (fixes 4.6x write amplification).
// ---------------------------------------------------------------------------
__global__ __launch_bounds__(256) void k_msg_base(
    const float* __restrict__ edge_attr,
    const float* __restrict__ W1, const float* __restrict__ b1,
    const float* __restrict__ W2, const float* __restrict__ b2,
    unsigned short* __restrict__ msg, int E)
{
    __shared__ unsigned short smem[256 * 72];   // 64 + 8 pad per row, 36 KB
    const int t = threadIdx.x;
    const int e = blockIdx.x * 256 + t;

    if (e < E) {
        float ea[EDIM];
        const float4* eap = reinterpret_cast<const float4*>(edge_attr + (size_t)e * EDIM);
        #pragma unroll
        for (int q = 0; q < EDIM / 4; ++q) {
            float4 v = eap[q];
            ea[q * 4 + 0] = v.x; ea[q * 4 + 1] = v.y;
            ea[q * 4 + 2] = v.z; ea[q * 4 + 3] = v.w;
        }

        float hid[HID];
        #pragma unroll
        for (int k = 0; k < HID; ++k) {
            float acc = b1[k];
            #pragma unroll
            for (int c = 0; c < EDIM; ++c) acc += ea[c] * W1[k * EDIM + c];
            hid[k] = acc > 0.f ? acc : 0.f;
        }

        for (int oc = 0; oc < HID; oc += 4) {     // oc uniform -> W2 via s_load
            float a0 = b2[oc + 0], a1 = b2[oc + 1], a2 = b2[oc + 2], a3 = b2[oc + 3];
            #pragma unroll
            for (int c = 0; c < HID; ++c) {
                float hv = hid[c];
                a0 += hv * W2[(oc + 0) * HID + c];
                a1 += hv * W2[(oc + 1) * HID + c];
                a2 += hv * W2[(oc + 2) * HID + c];
                a3 += hv * W2[(oc + 3) * HID + c];
            }
            smem[t * 72 + oc + 0] = f2bf(a0);
            smem[t * 72 + oc + 1] = f2bf(a1);
            smem[t * 72 + oc + 2] = f2bf(a2);
            smem[t * 72 + oc + 3] = f2bf(a3);
        }
    }
    __syncthreads();

    // coalesced write: block covers 256 edges * 64 ch = 32 KB contiguous
    const size_t base = (size_t)blockIdx.x * 256 * HID;
    #pragma unroll
    for (int k = 0; k < 16; ++k) {
        int flat  = k * 256 + t;                 // unit: 4 channels
        int e_loc = flat >> 4;
        int c4    = (flat & 15) * 4;
        if (blockIdx.x * 256 + e_loc < E) {
            ushort4 v = *reinterpret_cast<const ushort4*>(smem + e_loc * 72 + c4);
            *reinterpret_cast<ushort4*>(msg + base + (size_t)flat * 4) = v;
        }
    }
}

// ---------------------------------------------------------------------------
// K2: agg[dst] += msg[e] * h[src]. Thread = (edge, channel-pair): 32 thr/edge.
// bf16 msg read (4B/lane), fp32 h gather (8B/lane), packed bf16 atomic (1/thread).
// ---------------------------------------------------------------------------
__global__ __launch_bounds__(256) void k_scatter(
    const unsigned* __restrict__ msg2, const float* __restrict__ h,
    const int* __restrict__ ei, unsigned* __restrict__ agg2, int E)
{
    size_t gid = (size_t)blockIdx.x * 256 + threadIdx.x;
    int e  = (int)(gid >> 5);
    int c2 = (int)(gid & 31);
    if (e >= E) return;
    int dst = ei[e];
    int src = ei[E + e];
    unsigned m = msg2[(size_t)e * 32 + c2];
    float2 hv = *reinterpret_cast<const float2*>(h + (size_t)src * HID + c2 * 2);
    float p0 = bf2f((unsigned short)(m & 0xffffu)) * hv.x;
    float p1 = bf2f((unsigned short)(m >> 16))     * hv.y;
    unsigned pk = (unsigned)f2bf(p0) | ((unsigned)f2bf(p1) << 16);
    unsigned* addr = agg2 + (size_t)dst * 32 + c2;
    asm volatile("global_atomic_pk_add_bf16 %0, %1, off" :: "v"(addr), "v"(pk) : "memory");
}

// ---------------------------------------------------------------------------
// K3: h = GRUCell(agg, h) in place. Block = 64 nodes; wave p computes gate
// rows [16p,16p+16) for all 64 lanes' nodes -> weight rows wave-uniform
// (s_load). Load a/hh regs, barrier, compute, write own 64B slice.
// ---------------------------------------------------------------------------
__global__ __launch_bounds__(256) void k_gru(
    const unsigned* __restrict__ agg2, float* __restrict__ h,
    const float* __restrict__ W_ih, const float* __restrict__ b_ih,
    const float* __restrict__ W_hh, const float* __restrict__ b_hh, int N)
{
    const int lane = threadIdx.x & 63;
    const int p = __builtin_amdgcn_readfirstlane(threadIdx.x >> 6);
    const int n = blockIdx.x * 64 + lane;
    const bool act = (n < N);

    float a[HID], hh[HID];
    if (act) {
        const uint4* ap = reinterpret_cast<const uint4*>(agg2 + (size_t)n * 32);
        #pragma unroll
        for (int q = 0; q < 8; ++q) {
            uint4 v = ap[q];
            a[q * 8 + 0] = bf2f((unsigned short)(v.x & 0xffffu));
            a[q * 8 + 1] = bf2f((unsigned short)(v.x >> 16));
            a[q * 8 + 2] = bf2f((unsigned short)(v.y & 0xffffu));
            a[q * 8 + 3] = bf2f((unsigned short)(v.y >> 16));
            a[q * 8 + 4] = bf2f((unsigned short)(v.z & 0xffffu));
            a[q * 8 + 5] = bf2f((unsigned short)(v.z >> 16));
            a[q * 8 + 6] = bf2f((unsigned short)(v.w & 0xffffu));
            a[q * 8 + 7] = bf2f((unsigned short)(v.w >> 16));
        }
        const float4* hp = reinterpret_cast<const float4*>(h + (size_t)n * HID);
        #pragma unroll
        for (int q = 0; q < 16; ++q) {
            float4 v = hp[q];
            hh[q * 4 + 0] = v.x; hh[q * 4 + 1] = v.y;
            hh[q * 4 + 2] = v.z; hh[q * 4 + 3] = v.w;
        }
    }
    __syncthreads();   // everyone holds hh before anyone overwrites h
    if (!act) return;

    float out[16];
    for (int kk = 0; kk < 16; ++kk) {
        const int k = p * 16 + kk;              // uniform -> s_load weights
        float ir = b_ih[k], iz = b_ih[HID + k], inn = b_ih[2 * HID + k];
        float hr = b_hh[k], hz = b_hh[HID + k], hnn = b_hh[2 * HID + k];
        #pragma unroll
        for (int c = 0; c < HID; ++c) {
            float av = a[c], hv = hh[c];
            ir  += av * W_ih[(0 * HID + k) * HID + c];
            iz  += av * W_ih[(1 * HID + k) * HID + c];
            inn += av * W_ih[(2 * HID + k) * HID + c];
            hr  += hv * W_hh[(0 * HID + k) * HID + c];
            hz  += hv * W_hh[(1 * HID + k) * HID + c];
            hnn += hv * W_hh[(2 * HID + k) * HID + c];
        }
        float r = fast_sigmoid(ir + hr);
        float z = fast_sigmoid(iz + hz);
        float nn = fast_tanh(inn + r * hnn);
        out[kk] = (1.f - z) * nn + z * hh[k];
    }

    float4* op = reinterpret_cast<float4*>(h + (size_t)n * HID + p * 16);
    #pragma unroll
    for (int q = 0; q < 4; ++q) {
        float4 o;
        o.x = out[q * 4 + 0]; o.y = out[q * 4 + 1];
        o.z = out[q * 4 + 2]; o.w = out[q * 4 + 3];
        op[q] = o;
    }
}

extern "C" void kernel_launch(void* const* d_in, const int* in_sizes, int n_in,
                              void* d_out, int out_size, void* d_ws, size_t ws_size,
                              hipStream_t stream) {
    const float* h_in      = (const float*)d_in[0];
    const float* edge_attr = (const float*)d_in[1];
    const int*   ei        = (const int*)d_in[2];
    const float* W1        = (const float*)d_in[3];
    const float* b1        = (const float*)d_in[4];
    const float* W2        = (const float*)d_in[5];
    const float* b2        = (const float*)d_in[6];
    const float* W_ih      = (const float*)d_in[7];
    const float* b_ih      = (const float*)d_in[8];
    const float* W_hh      = (const float*)d_in[9];
    const float* b_hh      = (const float*)d_in[10];

    const int N = in_sizes[0] / HID;
    const int E = in_sizes[1] / EDIM;

    float* h = (float*)d_out;                                   // updated in place
    unsigned short* msg = (unsigned short*)d_ws;                // E*64 bf16 = 128 MB
    unsigned* agg2 = (unsigned*)((char*)d_ws + (size_t)E * HID * sizeof(unsigned short));

    hipMemcpyAsync(h, h_in, (size_t)N * HID * sizeof(float),
                   hipMemcpyDeviceToDevice, stream);

    k_msg_base<<<(E + 255) / 256, 256, 0, stream>>>(edge_attr, W1, b1, W2, b2, msg, E);

    for (int s = 0; s < NSTEPS; ++s) {
        hipMemsetAsync(agg2, 0, (size_t)N * 32 * sizeof(unsigned), stream);
        size_t total = (size_t)E * 32;
        k_scatter<<<(unsigned)((total + 255) / 256), 256, 0, stream>>>(
            (const unsigned*)msg, h, ei, agg2, E);
        k_gru<<<(N + 63) / 64, 256, 0, stream>>>(agg2, h, W_ih, b_ih, W_hh, b_hh, N);
    }
}

// Round 4
// 1991.732 us; speedup vs baseline: 2.0516x; 1.1442x over previous
//
#include <hip/hip_runtime.h>
#include <hip/hip_bf16.h>

#define HID 64
#define EDIM 32
#define NSTEPS 4

__device__ __forceinline__ float bf2f(unsigned short u) {
    union { unsigned u32; float f; } x; x.u32 = ((unsigned)u) << 16; return x.f;
}
__device__ __forceinline__ unsigned short f2bf(float f) {
    union { float f; unsigned u; } x; x.f = f;
    unsigned r = x.u + 0x7fff + ((x.u >> 16) & 1);   // RNE
    return (unsigned short)(r >> 16);
}
__device__ __forceinline__ float fast_sigmoid(float x) {
    return __builtin_amdgcn_rcpf(1.f + __expf(-x));
}
__device__ __forceinline__ float fast_tanh(float x) {
    return 1.f - 2.f * __builtin_amdgcn_rcpf(__expf(2.f * x) + 1.f);
}

// ---------------------------------------------------------------------------
// CSR build: histogram -> block scan -> global scan -> fill permutation
// ---------------------------------------------------------------------------
__global__ __launch_bounds__(256) void k_hist(
    const int* __restrict__ ei, int* __restrict__ cnt, int E)
{
    int e = blockIdx.x * 256 + threadIdx.x;
    if (e >= E) return;
    atomicAdd(&cnt[ei[e]], 1);
}

__global__ __launch_bounds__(256) void k_scan1(
    const int* __restrict__ cnt, int* __restrict__ tmp,
    int* __restrict__ partials, int N)
{
    __shared__ int s[256];
    int tid = threadIdx.x;
    int i = blockIdx.x * 256 + tid;
    int v = (i < N) ? cnt[i] : 0;
    s[tid] = v;
    __syncthreads();
    #pragma unroll
    for (int off = 1; off < 256; off <<= 1) {
        int t = (tid >= off) ? s[tid - off] : 0;
        __syncthreads();
        s[tid] += t;
        __syncthreads();
    }
    if (i < N) tmp[i] = s[tid] - v;              // exclusive within block
    if (tid == 255) partials[blockIdx.x] = s[255];
}

__global__ __launch_bounds__(512) void k_scan2(int* __restrict__ partials, int nb)
{
    __shared__ int s[512];
    int tid = threadIdx.x;
    int v = (tid < nb) ? partials[tid] : 0;
    s[tid] = v;
    __syncthreads();
    #pragma unroll
    for (int off = 1; off < 512; off <<= 1) {
        int t = (tid >= off) ? s[tid - off] : 0;
        __syncthreads();
        s[tid] += t;
        __syncthreads();
    }
    if (tid < nb) partials[tid] = s[tid] - v;    // exclusive across blocks
}

__global__ __launch_bounds__(256) void k_scan3(
    const int* __restrict__ tmp, const int* __restrict__ partials,
    int* __restrict__ row_ptr, int N, int E)
{
    int i = blockIdx.x * 256 + threadIdx.x;
    if (i < N) row_ptr[i] = tmp[i] + partials[i >> 8];
    if (i == 0) row_ptr[N] = E;
}

__global__ __launch_bounds__(256) void k_fill(
    const int* __restrict__ ei, int* __restrict__ cursor,
    int* __restrict__ posmap, int* __restrict__ src_perm, int E)
{
    int e = blockIdx.x * 256 + threadIdx.x;
    if (e >= E) return;
    int dst = ei[e];
    int src = ei[E + e];
    int pos = atomicAdd(&cursor[dst], 1);
    posmap[e] = pos;
    src_perm[pos] = src;
}

// ---------------------------------------------------------------------------
// K1: msg_perm[posmap[e]] = bf16(relu(ea @ W1^T + b1) @ W2^T + b2)
// fp32 compute, bf16 rows staged in LDS, written as full 128B-aligned rows
// in CSR-permuted order (8 lanes per row -> full-line writes, no amplification)
// ---------------------------------------------------------------------------
__global__ __launch_bounds__(256) void k_msg_base(
    const float* __restrict__ edge_attr,
    const float* __restrict__ W1, const float* __restrict__ b1,
    const float* __restrict__ W2, const float* __restrict__ b2,
    const int* __restrict__ posmap,
    unsigned short* __restrict__ msg_perm, int E)
{
    __shared__ unsigned short smem[256 * 72];   // 36 KB, 144B rows (16B aligned)
    __shared__ int spos[256];
    const int t = threadIdx.x;
    const int e = blockIdx.x * 256 + t;

    if (e < E) {
        spos[t] = posmap[e];

        float ea[EDIM];
        const float4* eap = reinterpret_cast<const float4*>(edge_attr + (size_t)e * EDIM);
        #pragma unroll
        for (int q = 0; q < EDIM / 4; ++q) {
            float4 v = eap[q];
            ea[q * 4 + 0] = v.x; ea[q * 4 + 1] = v.y;
            ea[q * 4 + 2] = v.z; ea[q * 4 + 3] = v.w;
        }

        float hid[HID];
        #pragma unroll
        for (int k = 0; k < HID; ++k) {
            float acc = b1[k];
            #pragma unroll
            for (int c = 0; c < EDIM; ++c) acc += ea[c] * W1[k * EDIM + c];
            hid[k] = acc > 0.f ? acc : 0.f;
        }

        for (int oc = 0; oc < HID; oc += 4) {     // oc uniform -> W2 via s_load
            float a0 = b2[oc + 0], a1 = b2[oc + 1], a2 = b2[oc + 2], a3 = b2[oc + 3];
            #pragma unroll
            for (int c = 0; c < HID; ++c) {
                float hv = hid[c];
                a0 += hv * W2[(oc + 0) * HID + c];
                a1 += hv * W2[(oc + 1) * HID + c];
                a2 += hv * W2[(oc + 2) * HID + c];
                a3 += hv * W2[(oc + 3) * HID + c];
            }
            smem[t * 72 + oc + 0] = f2bf(a0);
            smem[t * 72 + oc + 1] = f2bf(a1);
            smem[t * 72 + oc + 2] = f2bf(a2);
            smem[t * 72 + oc + 3] = f2bf(a3);
        }
    }
    __syncthreads();

    // write phase: 256 rows * 128B = 2048 chunks of 16B; 8 lanes cover a row
    #pragma unroll
    for (int it = 0; it < 8; ++it) {
        int flat  = it * 256 + t;
        int e_loc = flat >> 3;
        int c8    = (flat & 7) * 8;              // ushort offset within row
        if (blockIdx.x * 256 + e_loc < E) {
            uint4 v = *reinterpret_cast<const uint4*>(smem + e_loc * 72 + c8);
            size_t dst = (size_t)spos[e_loc] * HID + c8;
            *reinterpret_cast<uint4*>(msg_perm + dst) = v;
        }
    }
}

// ---------------------------------------------------------------------------
// K2: agg[n] = sum_{k in [row_ptr[n],row_ptr[n+1])} msg_perm[k] * h[src_perm[k]]
// One wave per node, lane = channel. Zero atomics, fp32 accumulate.
// ---------------------------------------------------------------------------
__global__ __launch_bounds__(256) void k_agg(
    const unsigned short* __restrict__ msg_perm, const float* __restrict__ h,
    const int* __restrict__ row_ptr, const int* __restrict__ src_perm,
    float* __restrict__ agg, int N)
{
    int wid  = blockIdx.x * 4 + (threadIdx.x >> 6);
    int lane = threadIdx.x & 63;
    if (wid >= N) return;
    int beg = row_ptr[wid];
    int end = row_ptr[wid + 1];
    float acc = 0.f;
    for (int k = beg; k < end; ++k) {
        int s = __builtin_amdgcn_readfirstlane(src_perm[k]);
        float m  = bf2f(msg_perm[(size_t)k * HID + lane]);
        float hv = h[(size_t)s * HID + lane];
        acc += m * hv;
    }
    agg[(size_t)wid * HID + lane] = acc;
}

// ---------------------------------------------------------------------------
// K3: h = GRUCell(agg, h) in place. Block = 64 nodes; wave p computes gate
// rows [16p,16p+16) -> weight rows wave-uniform (s_load).
// ---------------------------------------------------------------------------
__global__ __launch_bounds__(256) void k_gru(
    const float* __restrict__ agg, float* __restrict__ h,
    const float* __restrict__ W_ih, const float* __restrict__ b_ih,
    const float* __restrict__ W_hh, const float* __restrict__ b_hh, int N)
{
    const int lane = threadIdx.x & 63;
    const int p = __builtin_amdgcn_readfirstlane(threadIdx.x >> 6);
    const int n = blockIdx.x * 64 + lane;
    const bool act = (n < N);

    float a[HID], hh[HID];
    if (act) {
        const float4* ap = reinterpret_cast<const float4*>(agg + (size_t)n * HID);
        const float4* hp = reinterpret_cast<const float4*>(h + (size_t)n * HID);
        #pragma unroll
        for (int q = 0; q < 16; ++q) {
            float4 v = ap[q];
            a[q * 4 + 0] = v.x; a[q * 4 + 1] = v.y;
            a[q * 4 + 2] = v.z; a[q * 4 + 3] = v.w;
            float4 w = hp[q];
            hh[q * 4 + 0] = w.x; hh[q * 4 + 1] = w.y;
            hh[q * 4 + 2] = w.z; hh[q * 4 + 3] = w.w;
        }
    }
    __syncthreads();   // everyone holds hh before anyone overwrites h
    if (!act) return;

    float out[16];
    for (int kk = 0; kk < 16; ++kk) {
        const int k = p * 16 + kk;              // uniform -> s_load weights
        float ir = b_ih[k], iz = b_ih[HID + k], inn = b_ih[2 * HID + k];
        float hr = b_hh[k], hz = b_hh[HID + k], hnn = b_hh[2 * HID + k];
        #pragma unroll
        for (int c = 0; c < HID; ++c) {
            float av = a[c], hv = hh[c];
            ir  += av * W_ih[(0 * HID + k) * HID + c];
            iz  += av * W_ih[(1 * HID + k) * HID + c];
            inn += av * W_ih[(2 * HID + k) * HID + c];
            hr  += hv * W_hh[(0 * HID + k) * HID + c];
            hz  += hv * W_hh[(1 * HID + k) * HID + c];
            hnn += hv * W_hh[(2 * HID + k) * HID + c];
        }
        float r = fast_sigmoid(ir + hr);
        float z = fast_sigmoid(iz + hz);
        float nn = fast_tanh(inn + r * hnn);
        out[kk] = (1.f - z) * nn + z * hh[k];
    }

    float4* op = reinterpret_cast<float4*>(h + (size_t)n * HID + p * 16);
    #pragma unroll
    for (int q = 0; q < 4; ++q) {
        float4 o;
        o.x = out[q * 4 + 0]; o.y = out[q * 4 + 1];
        o.z = out[q * 4 + 2]; o.w = out[q * 4 + 3];
        op[q] = o;
    }
}

extern "C" void kernel_launch(void* const* d_in, const int* in_sizes, int n_in,
                              void* d_out, int out_size, void* d_ws, size_t ws_size,
                              hipStream_t stream) {
    const float* h_in      = (const float*)d_in[0];
    const float* edge_attr = (const float*)d_in[1];
    const int*   ei        = (const int*)d_in[2];
    const float* W1        = (const float*)d_in[3];
    const float* b1        = (const float*)d_in[4];
    const float* W2        = (const float*)d_in[5];
    const float* b2        = (const float*)d_in[6];
    const float* W_ih      = (const float*)d_in[7];
    const float* b_ih      = (const float*)d_in[8];
    const float* W_hh      = (const float*)d_in[9];
    const float* b_hh      = (const float*)d_in[10];

    const int N = in_sizes[0] / HID;
    const int E = in_sizes[1] / EDIM;
    const int NB = (N + 255) / 256;          // scan blocks (391 <= 512)

    float* h = (float*)d_out;                // h lives in d_out, updated in place

    // workspace layout
    char* base = (char*)d_ws;
    unsigned short* msg_perm = (unsigned short*)base;            // E*64*2 = 128 MB
    base += (size_t)E * HID * sizeof(unsigned short);
    float* agg = (float*)base;       base += (size_t)N * HID * sizeof(float);  // 25.6 MB
    int* row_ptr = (int*)base;       base += (size_t)(N + 1) * sizeof(int);
    int* cursor  = (int*)base;       base += (size_t)N * sizeof(int);
    int* cnt     = (int*)base;       base += (size_t)N * sizeof(int);
    int* tmp     = (int*)base;       base += (size_t)N * sizeof(int);
    int* partials= (int*)base;       base += 512 * sizeof(int);
    int* posmap  = (int*)base;       base += (size_t)E * sizeof(int);
    int* src_perm= (int*)base;

    hipMemcpyAsync(h, h_in, (size_t)N * HID * sizeof(float),
                   hipMemcpyDeviceToDevice, stream);

    // --- CSR build (once per launch; ws is re-poisoned every call) ---
    hipMemsetAsync(cnt, 0, (size_t)N * sizeof(int), stream);
    k_hist <<<(E + 255) / 256, 256, 0, stream>>>(ei, cnt, E);
    k_scan1<<<NB, 256, 0, stream>>>(cnt, tmp, partials, N);
    k_scan2<<<1, 512, 0, stream>>>(partials, NB);
    k_scan3<<<NB, 256, 0, stream>>>(tmp, partials, row_ptr, N, E);
    hipMemcpyAsync(cursor, row_ptr, (size_t)N * sizeof(int),
                   hipMemcpyDeviceToDevice, stream);
    k_fill <<<(E + 255) / 256, 256, 0, stream>>>(ei, cursor, posmap, src_perm, E);

    // --- step-invariant edge MLP, written in CSR order ---
    k_msg_base<<<(E + 255) / 256, 256, 0, stream>>>(
        edge_attr, W1, b1, W2, b2, posmap, msg_perm, E);

    for (int s = 0; s < NSTEPS; ++s) {
        k_agg<<<(N + 3) / 4, 256, 0, stream>>>(msg_perm, h, row_ptr, src_perm, agg, N);
        k_gru<<<(N + 63) / 64, 256, 0, stream>>>(agg, h, W_ih, b_ih, W_hh, b_hh, N);
    }
}